// Round 3
// baseline (1030.860 us; speedup 1.0000x reference)
//
#include <hip/hip_runtime.h>
#include <math.h>

typedef unsigned short u16;
typedef __bf16 bf16x8 __attribute__((ext_vector_type(8)));
typedef float f32x4 __attribute__((ext_vector_type(4)));

#define DEV static __device__ __forceinline__

DEV float b2f(u16 u) { union { unsigned int i; float f; } v; v.i = ((unsigned int)u) << 16; return v.f; }
DEV u16 f2b(float f) {
  union { float f; unsigned int i; } v; v.f = f;
  unsigned int x = v.i;
  unsigned int r = (x + 0x7fffu + ((x >> 16) & 1u)) >> 16;
  return (u16)r;
}
DEV bf16x8 load8bf(const u16* p) {
  union { uint4 u; bf16x8 b; } t;
  t.u = *(const uint4*)p;
  return t.b;
}
DEV float wave_sum(float x) {
  for (int m = 32; m >= 1; m >>= 1) x += __shfl_xor(x, m, 64);
  return x;
}
DEV float wave_max(float x) {
  for (int m = 32; m >= 1; m >>= 1) x = fmaxf(x, __shfl_xor(x, m, 64));
  return x;
}

// ---------------- dtype sniffer ----------------
__global__ __launch_bounds__(256) void detect_dtype(const u16* __restrict__ probe, int* __restrict__ flag) {
  __shared__ float red[4];
  int wave = threadIdx.x >> 6, lane = threadIdx.x & 63;
  float v = fabsf(b2f(probe[threadIdx.x]));
  v = wave_max(v);
  if (lane == 0) red[wave] = v;
  __syncthreads();
  if (threadIdx.x == 0) {
    float m = fmaxf(fmaxf(red[0], red[1]), fmaxf(red[2], red[3]));
    *flag = (m > 1e10f) ? 1 : 0;  // 1 => inputs are float32
  }
}

// ---------------- convert 9 small vectors to canonical bf16 ----------------
struct SmallCvt {
  const void* src[9];
  int n[9];
  int off[9];
};
__global__ __launch_bounds__(256) void cvt_small(SmallCvt s, u16* __restrict__ dst, const int* __restrict__ flagp) {
  int isf32 = *flagp;
  int a = blockIdx.x;
  const void* sp = s.src[a];
  for (int i = threadIdx.x; i < s.n[a]; i += 256) {
    float v = isf32 ? ((const float*)sp)[i] : b2f(((const u16*)sp)[i]);
    dst[s.off[a] + i] = f2b(v);
  }
}

// ---------------- fused LayerNorm(msa) -> canonical bf16 ----------------
__global__ __launch_bounds__(256) void ln_msa_k(const void* __restrict__ xv, const u16* __restrict__ g,
                                                const u16* __restrict__ b, u16* __restrict__ out,
                                                const int* __restrict__ flagp) {
  int isf32 = *flagp;
  int wave = threadIdx.x >> 6, lane = threadIdx.x & 63;
  size_t row = (size_t)blockIdx.x * 4 + wave;
  float f0, f1, f2, f3;
  if (isf32) {
    float4 v = *(const float4*)((const float*)xv + row * 256 + lane * 4);
    f0 = v.x; f1 = v.y; f2 = v.z; f3 = v.w;
  } else {
    ushort4 v = *(const ushort4*)((const u16*)xv + row * 256 + lane * 4);
    f0 = b2f(v.x); f1 = b2f(v.y); f2 = b2f(v.z); f3 = b2f(v.w);
  }
  float s = wave_sum(f0 + f1 + f2 + f3);
  float s2 = wave_sum(f0 * f0 + f1 * f1 + f2 * f2 + f3 * f3);
  float mean = s * (1.f / 256.f);
  float inv = rsqrtf(s2 * (1.f / 256.f) - mean * mean + 1e-5f);
  int c0 = lane * 4;
  ushort4 gv = *(const ushort4*)(g + c0);
  ushort4 bv = *(const ushort4*)(b + c0);
  ushort4 o;
  o.x = f2b((f0 - mean) * inv * b2f(gv.x) + b2f(bv.x));
  o.y = f2b((f1 - mean) * inv * b2f(gv.y) + b2f(bv.y));
  o.z = f2b((f2 - mean) * inv * b2f(gv.z) + b2f(bv.z));
  o.w = f2b((f3 - mean) * inv * b2f(gv.w) + b2f(bv.w));
  *(ushort4*)(out + row * 256 + c0) = o;
}

// ---------------- transpose seven 256x256 weight matrices -> bf16 ----------------
struct TransArgs {
  const void* src[7];
  u16* dst[7];
};
__global__ __launch_bounds__(256) void transpose_w(TransArgs t, const int* __restrict__ flagp) {
  __shared__ float tile[32][33];
  int isf32 = *flagp;
  int m = blockIdx.z;
  const void* s = t.src[m];
  u16* d = t.dst[m];
  int bx = blockIdx.x * 32, by = blockIdx.y * 32;
  int c = threadIdx.x & 31, r0 = threadIdx.x >> 5;
  for (int rr = r0; rr < 32; rr += 8) {
    int idx = (by + rr) * 256 + bx + c;
    tile[rr][c] = isf32 ? ((const float*)s)[idx] : b2f(((const u16*)s)[idx]);
  }
  __syncthreads();
  for (int rr = r0; rr < 32; rr += 8) d[(bx + rr) * 256 + by + c] = f2b(tile[c][rr]);
}

// ---------------- GEMM: out[rows,256] = f((A @ W + bias) * alpha) ----------------
// A is canonical bf16 (pre-LayerNormed).
// mode: 0 = store, 1 = sigmoid-gate RMW, 2 = multiply by seq_weight then store,
//       3 = store transposed into vt layout (for the v projection).
// If WT2 != nullptr the y-grid is 4: y<2 computes WT->outv, y>=2 computes WT2->out2
// (mode_b/alpha_b), sharing the A fetch.
__global__ __launch_bounds__(256) void gemmA(const u16* __restrict__ A, size_t aoff,
                                             const u16* __restrict__ WT, const u16* __restrict__ bias,
                                             void* __restrict__ outv, size_t ooff, int mode, float alpha,
                                             const float* __restrict__ sw, int n0sw,
                                             const int* __restrict__ flagp, int out_flag,
                                             const u16* __restrict__ WT2, void* __restrict__ out2,
                                             int mode_b, float alpha_b) {
  int isf32 = *flagp;
  int n0;
  if (WT2) {
    if (blockIdx.y >> 1) { WT = WT2; outv = out2; mode = mode_b; alpha = alpha_b; bias = nullptr; }
    n0 = (blockIdx.y & 1) * 128;
  } else {
    n0 = blockIdx.y * 128;
  }
  int i0 = blockIdx.x * 128;
  int wave = threadIdx.x >> 6, lane = threadIdx.x & 63;
  int wr = wave >> 1, wc = wave & 1;
  int l15 = lane & 15, quad = lane >> 4;
  const f32x4 fz = {0.f, 0.f, 0.f, 0.f};
  f32x4 acc[4][4];
  for (int mi = 0; mi < 4; ++mi)
    for (int ni = 0; ni < 4; ++ni) acc[mi][ni] = fz;
  int arow = i0 + wr * 64 + l15;
  int brow = n0 + wc * 64 + l15;
  const u16* ap = A + (aoff + (size_t)arow) * 256 + quad * 8;
  const u16* bp = WT + (size_t)brow * 256 + quad * 8;
  for (int k0 = 0; k0 < 256; k0 += 32) {
    bf16x8 a[4], b[4];
#pragma unroll
    for (int mi = 0; mi < 4; ++mi) a[mi] = load8bf(ap + mi * 16 * 256 + k0);
#pragma unroll
    for (int ni = 0; ni < 4; ++ni) b[ni] = load8bf(bp + ni * 16 * 256 + k0);
#pragma unroll
    for (int mi = 0; mi < 4; ++mi)
#pragma unroll
      for (int ni = 0; ni < 4; ++ni)
        acc[mi][ni] = __builtin_amdgcn_mfma_f32_16x16x32_bf16(a[mi], b[ni], acc[mi][ni], 0, 0, 0);
  }
  int f32out = out_flag && isf32;
  int nloc = blockIdx.x / 3;  // local MSA-row index within chunk (each 384-row slab = 3 x-blocks)
  if (mode == 3) {
    // write v transposed: vt[(nloc*256 + col)][i] ; 4 acc rows are 4 consecutive i
#pragma unroll
    for (int mi = 0; mi < 4; ++mi) {
      int ib = i0 + wr * 64 + mi * 16 + quad * 4 - nloc * 384;
#pragma unroll
      for (int ni = 0; ni < 4; ++ni) {
        int col = n0 + wc * 64 + ni * 16 + l15;
        ushort4 o;
        o.x = f2b(acc[mi][ni][0]);
        o.y = f2b(acc[mi][ni][1]);
        o.z = f2b(acc[mi][ni][2]);
        o.w = f2b(acc[mi][ni][3]);
        *(ushort4*)((u16*)outv + ((size_t)(nloc * 256 + col)) * 384 + ib) = o;
      }
    }
    return;
  }
#pragma unroll
  for (int mi = 0; mi < 4; ++mi) {
    int rbase = i0 + wr * 64 + mi * 16 + quad * 4;
#pragma unroll
    for (int ni = 0; ni < 4; ++ni) {
      int col = n0 + wc * 64 + ni * 16 + l15;
      float bv = bias ? b2f(bias[col]) : 0.f;
#pragma unroll
      for (int r = 0; r < 4; ++r) {
        float val = (acc[mi][ni][r] + bv) * alpha;
        if (mode == 2) {
          int i = rbase - nloc * 384 + r;  // residue index within L
          int h = col >> 5;                // head
          val *= sw[((size_t)(i * 8 + h)) * 256 + (n0sw + nloc)];
        }
        size_t idx = (ooff + (size_t)(rbase + r)) * 256 + col;
        if (mode == 1) {
          float gate = 1.f / (1.f + expf(-val));
          ((u16*)outv)[idx] = f2b(b2f(((u16*)outv)[idx]) * gate);
        } else if (f32out) {
          ((float*)outv)[idx] = val;
        } else {
          ((u16*)outv)[idx] = f2b(val);
        }
      }
    }
  }
}

// ---------------- SequenceWeight logits (chunked) ----------------
__global__ __launch_bounds__(256) void sw_logits_c(const u16* __restrict__ qsw, const u16* __restrict__ kswc,
                                                   float* __restrict__ swlog, int n0) {
  int nl = blockIdx.y;
  int t = blockIdx.x * 256 + threadIdx.x;
  int i = t >> 3, h = t & 7;
  const u16* kr = kswc + ((size_t)(nl * 384 + i)) * 256 + h * 32;
  const u16* qr = qsw + (size_t)i * 256 + h * 32;
  float dot = 0.f;
#pragma unroll
  for (int d8 = 0; d8 < 4; ++d8) {
    union { uint4 u; u16 us[8]; } ku, qu;
    ku.u = *(const uint4*)(kr + d8 * 8);
    qu.u = *(const uint4*)(qr + d8 * 8);
#pragma unroll
    for (int j = 0; j < 8; ++j) dot += b2f(ku.us[j]) * b2f(qu.us[j]);
  }
  swlog[(size_t)(i * 8 + h) * 256 + n0 + nl] = dot;
}

// ---------------- softmax over n (256) ----------------
__global__ __launch_bounds__(256) void sw_softmax(float* __restrict__ swlog) {
  __shared__ float red[4];
  float* p = swlog + (size_t)blockIdx.x * 256;
  int wave = threadIdx.x >> 6, lane = threadIdx.x & 63;
  float x = p[threadIdx.x];
  float m = wave_max(x);
  if (lane == 0) red[wave] = m;
  __syncthreads();
  float mx = fmaxf(fmaxf(red[0], red[1]), fmaxf(red[2], red[3]));
  __syncthreads();
  float e = expf(x - mx);
  float s = wave_sum(e);
  if (lane == 0) red[wave] = s;
  __syncthreads();
  float sum = red[0] + red[1] + red[2] + red[3];
  p[threadIdx.x] = e / sum;
}

// ---------------- pair LayerNorm + @wb -> attn bias ----------------
__global__ __launch_bounds__(256) void pair_bias(const void* __restrict__ pairv, const u16* __restrict__ g,
                                                 const u16* __restrict__ b, const u16* __restrict__ wb,
                                                 float* __restrict__ attn, const int* __restrict__ flagp) {
  int isf32 = *flagp;
  int wave = threadIdx.x >> 6, lane = threadIdx.x & 63;
  size_t row = (size_t)blockIdx.x * 4 + wave;
  float v0, v1;
  if (isf32) {
    const float* pf = (const float*)pairv + row * 128 + lane * 2;
    v0 = pf[0]; v1 = pf[1];
  } else {
    const u16* pr = (const u16*)pairv + row * 128 + lane * 2;
    v0 = b2f(pr[0]); v1 = b2f(pr[1]);
  }
  float s = wave_sum(v0 + v1);
  float s2 = wave_sum(v0 * v0 + v1 * v1);
  float mean = s * (1.f / 128.f);
  float var = s2 * (1.f / 128.f) - mean * mean;
  float inv = rsqrtf(var + 1e-5f);
  int c0 = lane * 2;
  v0 = (v0 - mean) * inv * b2f(g[c0]) + b2f(b[c0]);
  v1 = (v1 - mean) * inv * b2f(g[c0 + 1]) + b2f(b[c0 + 1]);
  float ph[8];
  const u16* w0 = wb + c0 * 8;
#pragma unroll
  for (int h = 0; h < 8; ++h) ph[h] = v0 * b2f(w0[h]) + v1 * b2f(w0[8 + h]);
#pragma unroll
  for (int m = 32; m >= 1; m >>= 1)
#pragma unroll
    for (int h = 0; h < 8; ++h) ph[h] += __shfl_xor(ph[h], m, 64);
  if (lane == 0) {
#pragma unroll
    for (int h = 0; h < 8; ++h) attn[(size_t)h * 147456 + row] = ph[h];
  }
}

// ---------------- QK chunk ----------------
__global__ __launch_bounds__(256) void qk_accum_c(const u16* __restrict__ qc, const u16* __restrict__ kc,
                                                  float* __restrict__ attn, int nlen) {
  int h = blockIdx.y;
  int i0 = (blockIdx.x % 3) * 128, j0 = (blockIdx.x / 3) * 128;
  int nb = blockIdx.z * nlen;
  int wave = threadIdx.x >> 6, lane = threadIdx.x & 63;
  int wr = wave >> 1, wc = wave & 1;
  int l15 = lane & 15, quad = lane >> 4;
  const f32x4 fz = {0.f, 0.f, 0.f, 0.f};
  f32x4 acc[4][4];
  for (int mi = 0; mi < 4; ++mi)
    for (int ni = 0; ni < 4; ++ni) acc[mi][ni] = fz;
  int arow = i0 + wr * 64 + l15;
  int brow = j0 + wc * 64 + l15;
  for (int n = nb; n < nb + nlen; ++n) {
    size_t base = (size_t)n * 384;
    const u16* ap = qc + (base + arow) * 256 + h * 32 + quad * 8;
    const u16* bp = kc + (base + brow) * 256 + h * 32 + quad * 8;
    bf16x8 a[4], b[4];
#pragma unroll
    for (int mi = 0; mi < 4; ++mi) a[mi] = load8bf(ap + mi * 16 * 256);
#pragma unroll
    for (int ni = 0; ni < 4; ++ni) b[ni] = load8bf(bp + ni * 16 * 256);
#pragma unroll
    for (int mi = 0; mi < 4; ++mi)
#pragma unroll
      for (int ni = 0; ni < 4; ++ni)
        acc[mi][ni] = __builtin_amdgcn_mfma_f32_16x16x32_bf16(a[mi], b[ni], acc[mi][ni], 0, 0, 0);
  }
#pragma unroll
  for (int mi = 0; mi < 4; ++mi)
#pragma unroll
    for (int ni = 0; ni < 4; ++ni) {
      int i = i0 + wr * 64 + mi * 16 + quad * 4;
      int j = j0 + wc * 64 + ni * 16 + l15;
#pragma unroll
      for (int r = 0; r < 4; ++r)
        atomicAdd(&attn[(size_t)h * 147456 + (size_t)(i + r) * 384 + j], acc[mi][ni][r]);
    }
}

// ---------------- softmax over j (384) -> bf16 ----------------
__global__ __launch_bounds__(384) void attn_softmax_k(const float* __restrict__ attn, u16* __restrict__ attn_bf) {
  __shared__ float red[6];
  size_t r = blockIdx.x;
  const float* p = attn + r * 384;
  int wave = threadIdx.x >> 6, lane = threadIdx.x & 63;
  float x = p[threadIdx.x];
  float m = wave_max(x);
  if (lane == 0) red[wave] = m;
  __syncthreads();
  float mx = red[0];
#pragma unroll
  for (int i = 1; i < 6; ++i) mx = fmaxf(mx, red[i]);
  __syncthreads();
  float e = expf(x - mx);
  float s = wave_sum(e);
  if (lane == 0) red[wave] = s;
  __syncthreads();
  float sum = 0.f;
#pragma unroll
  for (int i = 0; i < 6; ++i) sum += red[i];
  attn_bf[r * 384 + threadIdx.x] = f2b(e / sum);
}

// ---------------- PV as batched GEMM: per h, O = attn[h] (384x384) @ V (384 x NC*32) ----------------
// B^T is vt: row (nl*256 + h*32 + d) holds 384 j-contiguous values.
__global__ __launch_bounds__(256) void pv_gemm(const u16* __restrict__ attn_bf, const u16* __restrict__ vt,
                                               u16* __restrict__ oc) {
  int h = blockIdx.z;
  int i0 = blockIdx.x * 128;  // over i = 384
  int c0 = blockIdx.y * 128;  // over cols = NC*32 (n*32+d)
  int wave = threadIdx.x >> 6, lane = threadIdx.x & 63;
  int wr = wave >> 1, wc = wave & 1;
  int l15 = lane & 15, quad = lane >> 4;
  const f32x4 fz = {0.f, 0.f, 0.f, 0.f};
  f32x4 acc[4][4];
  for (int mi = 0; mi < 4; ++mi)
    for (int ni = 0; ni < 4; ++ni) acc[mi][ni] = fz;
  int arow = i0 + wr * 64 + l15;
  const u16* ap = attn_bf + ((size_t)(h * 384 + arow)) * 384 + quad * 8;
  const u16* bp[4];
#pragma unroll
  for (int ni = 0; ni < 4; ++ni) {
    int col = c0 + wc * 64 + ni * 16 + l15;
    bp[ni] = vt + ((size_t)((col >> 5) * 256 + h * 32 + (col & 31))) * 384 + quad * 8;
  }
  for (int k0 = 0; k0 < 384; k0 += 32) {
    bf16x8 a[4], b[4];
#pragma unroll
    for (int mi = 0; mi < 4; ++mi) a[mi] = load8bf(ap + mi * 16 * 384 + k0);
#pragma unroll
    for (int ni = 0; ni < 4; ++ni) b[ni] = load8bf(bp[ni] + k0);
#pragma unroll
    for (int mi = 0; mi < 4; ++mi)
#pragma unroll
      for (int ni = 0; ni < 4; ++ni)
        acc[mi][ni] = __builtin_amdgcn_mfma_f32_16x16x32_bf16(a[mi], b[ni], acc[mi][ni], 0, 0, 0);
  }
#pragma unroll
  for (int mi = 0; mi < 4; ++mi) {
    int ib = i0 + wr * 64 + mi * 16 + quad * 4;
#pragma unroll
    for (int ni = 0; ni < 4; ++ni) {
      int col = c0 + wc * 64 + ni * 16 + l15;
      int nl = col >> 5, d = col & 31;
#pragma unroll
      for (int r = 0; r < 4; ++r)
        oc[((size_t)(nl * 384 + ib + r)) * 256 + h * 32 + d] = f2b(acc[mi][ni][r]);
    }
  }
}

extern "C" void kernel_launch(void* const* d_in, const int* in_sizes, int n_in,
                              void* d_out, int out_size, void* d_ws, size_t ws_size,
                              hipStream_t stream) {
  const void* msa = d_in[0];
  const void* pair = d_in[1];
  const void* ln_msa_g = d_in[2];
  const void* ln_msa_b = d_in[3];
  const void* ln_pair_g = d_in[4];
  const void* ln_pair_b = d_in[5];
  const void* sw_wq = d_in[6];
  const void* sw_bq = d_in[7];
  const void* sw_wk = d_in[8];
  const void* sw_bk = d_in[9];
  const void* wq = d_in[10];
  const void* wk = d_in[11];
  const void* wv = d_in[12];
  const void* wb = d_in[13];
  const void* wg = d_in[14];
  const void* bg = d_in[15];
  const void* wo = d_in[16];
  const void* bo = d_in[17];

  char* ws = (char*)d_ws;
  int* flag = (int*)ws;                   //      256 B @ 0
  float* swlog = (float*)(ws + 256);      //  3145728 B
  float* attnf = (float*)(ws + 3145984);  //  4718592 B
  u16* wT = (u16*)(ws + 7864576);         //   917504 B
  u16* qswb = (u16*)(ws + 8782080);       //   196608 B
  u16* attnbf = (u16*)(ws + 8978688);     //  2359296 B
  u16* smallv = (u16*)(ws + 11337984);    //     5632 B
  u16* mbf = (u16*)(ws + 11343616);       // 50331648 B  (LN(msa) in bf16)
  const size_t SMALLS = 61675264ull;
  u16* c_lng = smallv + 0;
  u16* c_lnb = smallv + 256;
  u16* c_lpg = smallv + 512;
  u16* c_lpb = smallv + 640;
  u16* c_sbq = smallv + 768;
  u16* c_sbk = smallv + 1024;
  u16* c_bg = smallv + 1280;
  u16* c_bo = smallv + 1536;
  u16* c_wb = smallv + 1792;

  int NC = 256;
  while (NC > 8 && SMALLS + 3ull * (size_t)NC * 196608ull > ws_size) NC >>= 1;
  const size_t CBsz = (size_t)NC * 196608ull;
  u16* CB1 = (u16*)(ws + SMALLS);
  u16* CB2 = (u16*)(ws + SMALLS + CBsz);
  u16* CB3 = (u16*)(ws + SMALLS + 2 * CBsz);
  const int nchunks = 256 / NC;
  const int nlen = 8;  // fine z-split: NC/8 n-partitions -> high occupancy for qk

  const float isd = 0.17677669529663687f;  // 1/sqrt(32)

  detect_dtype<<<1, 256, 0, stream>>>((const u16*)msa, flag);

  SmallCvt sc;
  sc.src[0] = ln_msa_g;  sc.n[0] = 256;  sc.off[0] = 0;
  sc.src[1] = ln_msa_b;  sc.n[1] = 256;  sc.off[1] = 256;
  sc.src[2] = ln_pair_g; sc.n[2] = 128;  sc.off[2] = 512;
  sc.src[3] = ln_pair_b; sc.n[3] = 128;  sc.off[3] = 640;
  sc.src[4] = sw_bq;     sc.n[4] = 256;  sc.off[4] = 768;
  sc.src[5] = sw_bk;     sc.n[5] = 256;  sc.off[5] = 1024;
  sc.src[6] = bg;        sc.n[6] = 256;  sc.off[6] = 1280;
  sc.src[7] = bo;        sc.n[7] = 256;  sc.off[7] = 1536;
  sc.src[8] = wb;        sc.n[8] = 1024; sc.off[8] = 1792;
  cvt_small<<<9, 256, 0, stream>>>(sc, smallv, flag);

  TransArgs ta;
  ta.src[0] = sw_wq; ta.src[1] = sw_wk; ta.src[2] = wq; ta.src[3] = wk;
  ta.src[4] = wv;    ta.src[5] = wg;    ta.src[6] = wo;
  for (int i = 0; i < 7; ++i) ta.dst[i] = wT + i * 65536;
  transpose_w<<<dim3(8, 8, 7), 256, 0, stream>>>(ta, flag);

  // LN(msa) -> bf16 once; all projections consume this.
  ln_msa_k<<<24576, 256, 0, stream>>>(msa, c_lng, c_lnb, mbf, flag);

  // qsw = (LN(msa)[:,0] @ sw_wq + sw_bq) * isd
  gemmA<<<dim3(3, 2), 256, 0, stream>>>(mbf, 0, wT + 0 * 65536, c_sbq,
                                        qswb, 0, 0, isd, nullptr, 0, flag, 0,
                                        nullptr, nullptr, 0, 0.f);

  for (int c = 0; c < nchunks; ++c) {
    size_t R = (size_t)c * NC * 384;
    gemmA<<<dim3(3 * NC, 2), 256, 0, stream>>>(mbf, R, wT + 1 * 65536, c_sbk,
                                               CB1, 0, 0, 1.f, nullptr, 0, flag, 0,
                                               nullptr, nullptr, 0, 0.f);
    sw_logits_c<<<dim3(12, NC), 256, 0, stream>>>(qswb, CB1, swlog, c * NC);
  }
  sw_softmax<<<3072, 256, 0, stream>>>(swlog);

  pair_bias<<<36864, 256, 0, stream>>>(pair, c_lpg, c_lpb, c_wb, attnf, flag);
  for (int c = 0; c < nchunks; ++c) {
    size_t R = (size_t)c * NC * 384;
    // fused: q = LN(msa)@wq (mode 2, seq-weight in epilogue) -> CB1
    //        k = LN(msa)@wk * isd                             -> CB2
    gemmA<<<dim3(3 * NC, 4), 256, 0, stream>>>(mbf, R, wT + 2 * 65536, nullptr,
                                               CB1, 0, 2, 1.f, swlog, c * NC, flag, 0,
                                               wT + 3 * 65536, CB2, 0, isd);
    qk_accum_c<<<dim3(9, 8, NC / nlen), 256, 0, stream>>>(CB1, CB2, attnf, nlen);
  }
  attn_softmax_k<<<3072, 384, 0, stream>>>(attnf, attnbf);

  for (int c = 0; c < nchunks; ++c) {
    size_t R = (size_t)c * NC * 384;
    // v = LN(msa) @ wv, written directly in vt (transposed) layout via mode 3
    gemmA<<<dim3(3 * NC, 2), 256, 0, stream>>>(mbf, R, wT + 4 * 65536, nullptr,
                                               CB2, 0, 3, 1.f, nullptr, 0, flag, 0,
                                               nullptr, nullptr, 0, 0.f);
    pv_gemm<<<dim3(3, NC / 4, 8), 256, 0, stream>>>(attnbf, CB2, CB3);
    gemmA<<<dim3(3 * NC, 2), 256, 0, stream>>>(mbf, R, wT + 5 * 65536, c_bg,
                                               CB3, 0, 1, 1.f, nullptr, 0, flag, 0,
                                               nullptr, nullptr, 0, 0.f);
    gemmA<<<dim3(3 * NC, 2), 256, 0, stream>>>(CB3, 0, wT + 6 * 65536, c_bo,
                                               d_out, R, 0, 1.f, nullptr, 0, flag, 1,
                                               nullptr, nullptr, 0, 0.f);
  }
}

// Round 4
// 865.722 us; speedup vs baseline: 1.1908x; 1.1908x over previous
//
#include <hip/hip_runtime.h>
#include <math.h>

typedef unsigned short u16;
typedef __bf16 bf16x8 __attribute__((ext_vector_type(8)));
typedef float f32x4 __attribute__((ext_vector_type(4)));

#define DEV static __device__ __forceinline__

DEV float b2f(u16 u) { union { unsigned int i; float f; } v; v.i = ((unsigned int)u) << 16; return v.f; }
DEV u16 f2b(float f) {
  union { float f; unsigned int i; } v; v.f = f;
  unsigned int x = v.i;
  unsigned int r = (x + 0x7fffu + ((x >> 16) & 1u)) >> 16;
  return (u16)r;
}
DEV bf16x8 load8bf(const u16* p) {
  union { uint4 u; bf16x8 b; } t;
  t.u = *(const uint4*)p;
  return t.b;
}
// async global->LDS, 16 bytes per lane (dest must be wave-uniform base + lane*16)
DEV void gl_lds16(const u16* g, u16* l) {
  __builtin_amdgcn_global_load_lds((const __attribute__((address_space(1))) unsigned int*)g,
                                   (__attribute__((address_space(3))) unsigned int*)l, 16, 0, 0);
}
DEV float wave_sum(float x) {
  for (int m = 32; m >= 1; m >>= 1) x += __shfl_xor(x, m, 64);
  return x;
}
DEV float wave_max(float x) {
  for (int m = 32; m >= 1; m >>= 1) x = fmaxf(x, __shfl_xor(x, m, 64));
  return x;
}

// ---------------- dtype sniffer ----------------
__global__ __launch_bounds__(256) void detect_dtype(const u16* __restrict__ probe, int* __restrict__ flag) {
  __shared__ float red[4];
  int wave = threadIdx.x >> 6, lane = threadIdx.x & 63;
  float v = fabsf(b2f(probe[threadIdx.x]));
  v = wave_max(v);
  if (lane == 0) red[wave] = v;
  __syncthreads();
  if (threadIdx.x == 0) {
    float m = fmaxf(fmaxf(red[0], red[1]), fmaxf(red[2], red[3]));
    *flag = (m > 1e10f) ? 1 : 0;  // 1 => inputs are float32
  }
}

// ---------------- convert 9 small vectors to canonical bf16 ----------------
struct SmallCvt {
  const void* src[9];
  int n[9];
  int off[9];
};
__global__ __launch_bounds__(256) void cvt_small(SmallCvt s, u16* __restrict__ dst, const int* __restrict__ flagp) {
  int isf32 = *flagp;
  int a = blockIdx.x;
  const void* sp = s.src[a];
  for (int i = threadIdx.x; i < s.n[a]; i += 256) {
    float v = isf32 ? ((const float*)sp)[i] : b2f(((const u16*)sp)[i]);
    dst[s.off[a] + i] = f2b(v);
  }
}

// ---------------- fused LayerNorm(msa) -> canonical bf16 ----------------
__global__ __launch_bounds__(256) void ln_msa_k(const void* __restrict__ xv, const u16* __restrict__ g,
                                                const u16* __restrict__ b, u16* __restrict__ out,
                                                const int* __restrict__ flagp) {
  int isf32 = *flagp;
  int wave = threadIdx.x >> 6, lane = threadIdx.x & 63;
  size_t row = (size_t)blockIdx.x * 4 + wave;
  float f0, f1, f2, f3;
  if (isf32) {
    float4 v = *(const float4*)((const float*)xv + row * 256 + lane * 4);
    f0 = v.x; f1 = v.y; f2 = v.z; f3 = v.w;
  } else {
    ushort4 v = *(const ushort4*)((const u16*)xv + row * 256 + lane * 4);
    f0 = b2f(v.x); f1 = b2f(v.y); f2 = b2f(v.z); f3 = b2f(v.w);
  }
  float s = wave_sum(f0 + f1 + f2 + f3);
  float s2 = wave_sum(f0 * f0 + f1 * f1 + f2 * f2 + f3 * f3);
  float mean = s * (1.f / 256.f);
  float inv = rsqrtf(s2 * (1.f / 256.f) - mean * mean + 1e-5f);
  int c0 = lane * 4;
  ushort4 gv = *(const ushort4*)(g + c0);
  ushort4 bv = *(const ushort4*)(b + c0);
  ushort4 o;
  o.x = f2b((f0 - mean) * inv * b2f(gv.x) + b2f(bv.x));
  o.y = f2b((f1 - mean) * inv * b2f(gv.y) + b2f(bv.y));
  o.z = f2b((f2 - mean) * inv * b2f(gv.z) + b2f(bv.z));
  o.w = f2b((f3 - mean) * inv * b2f(gv.w) + b2f(bv.w));
  *(ushort4*)(out + row * 256 + c0) = o;
}

// ---------------- transpose seven 256x256 weight matrices -> bf16 ----------------
struct TransArgs {
  const void* src[7];
  u16* dst[7];
};
__global__ __launch_bounds__(256) void transpose_w(TransArgs t, const int* __restrict__ flagp) {
  __shared__ float tile[32][33];
  int isf32 = *flagp;
  int m = blockIdx.z;
  const void* s = t.src[m];
  u16* d = t.dst[m];
  int bx = blockIdx.x * 32, by = blockIdx.y * 32;
  int c = threadIdx.x & 31, r0 = threadIdx.x >> 5;
  for (int rr = r0; rr < 32; rr += 8) {
    int idx = (by + rr) * 256 + bx + c;
    tile[rr][c] = isf32 ? ((const float*)s)[idx] : b2f(((const u16*)s)[idx]);
  }
  __syncthreads();
  for (int rr = r0; rr < 32; rr += 8) d[(bx + rr) * 256 + by + c] = f2b(tile[c][rr]);
}

// ---------------- GEMM: out[rows,256] = f((A @ W + bias) * alpha) ----------------
// LDS-staged (global_load_lds w16) 128x128 tile, BK=64, XOR-swizzled LDS layout:
//   u16 index of element (row, k) = row*64 + (k ^ ((row&7)<<3))
// mode: 0 = store, 1 = sigmoid-gate RMW, 2 = multiply by seq_weight then store,
//       3 = store transposed into vt layout (for the v projection).
// If WT2 != nullptr the y-grid is 4: y<2 computes WT->outv, y>=2 computes WT2->out2.
__global__ __launch_bounds__(256) void gemmA(const u16* __restrict__ A, size_t aoff,
                                             const u16* __restrict__ WT, const u16* __restrict__ bias,
                                             void* __restrict__ outv, size_t ooff, int mode, float alpha,
                                             const float* __restrict__ sw, int n0sw,
                                             const int* __restrict__ flagp, int out_flag,
                                             const u16* __restrict__ WT2, void* __restrict__ out2,
                                             int mode_b, float alpha_b) {
  __shared__ u16 As[128 * 64];
  __shared__ u16 Bs[128 * 64];
  int isf32 = *flagp;
  int n0;
  if (WT2) {
    if (blockIdx.y >> 1) { WT = WT2; outv = out2; mode = mode_b; alpha = alpha_b; bias = nullptr; }
    n0 = (blockIdx.y & 1) * 128;
  } else {
    n0 = blockIdx.y * 128;
  }
  int i0 = blockIdx.x * 128;
  int t = threadIdx.x;
  int wave = t >> 6, lane = t & 63;
  int wr = wave >> 1, wc = wave & 1;
  int l15 = lane & 15, quad = lane >> 4;
  const f32x4 fz = {0.f, 0.f, 0.f, 0.f};
  f32x4 acc[4][4];
  for (int mi = 0; mi < 4; ++mi)
    for (int ni = 0; ni < 4; ++ni) acc[mi][ni] = fz;
  // staging: thread t, pass p stages 16B; LDS row = t/8 + p*32, swizzled source col:
  int srow = t >> 3;
  int scol = ((t & 7) ^ (srow & 7)) * 8;  // pre-swizzled global col so LDS lands swizzled
  const u16* ga = A + (aoff + (size_t)(i0 + srow)) * 256 + scol;
  const u16* gb = WT + ((size_t)(n0 + srow)) * 256 + scol;
  u16* la = As + t * 8;
  u16* lb = Bs + t * 8;
  for (int k0 = 0; k0 < 256; k0 += 64) {
    __syncthreads();  // protect LDS from readers of previous K-step
#pragma unroll
    for (int p = 0; p < 4; ++p) {
      gl_lds16(ga + (size_t)p * 32 * 256 + k0, la + p * 2048);
      gl_lds16(gb + (size_t)p * 32 * 256 + k0, lb + p * 2048);
    }
    __syncthreads();  // drains vmcnt, publishes LDS
#pragma unroll
    for (int kk = 0; kk < 2; ++kk) {
      bf16x8 a[4], b[4];
      int kc = kk * 32 + quad * 8;
#pragma unroll
      for (int mi = 0; mi < 4; ++mi) {
        int row = wr * 64 + mi * 16 + l15;
        a[mi] = load8bf(As + row * 64 + (kc ^ ((row & 7) << 3)));
      }
#pragma unroll
      for (int ni = 0; ni < 4; ++ni) {
        int row = wc * 64 + ni * 16 + l15;
        b[ni] = load8bf(Bs + row * 64 + (kc ^ ((row & 7) << 3)));
      }
#pragma unroll
      for (int mi = 0; mi < 4; ++mi)
#pragma unroll
        for (int ni = 0; ni < 4; ++ni)
          acc[mi][ni] = __builtin_amdgcn_mfma_f32_16x16x32_bf16(a[mi], b[ni], acc[mi][ni], 0, 0, 0);
    }
  }
  int f32out = out_flag && isf32;
  int nloc = blockIdx.x / 3;  // local MSA-row index within chunk (each 384-row slab = 3 x-blocks)
  if (mode == 3) {
    // write v transposed: vt[(nloc*256 + col)][i] ; 4 acc rows are 4 consecutive i
#pragma unroll
    for (int mi = 0; mi < 4; ++mi) {
      int ib = i0 + wr * 64 + mi * 16 + quad * 4 - nloc * 384;
#pragma unroll
      for (int ni = 0; ni < 4; ++ni) {
        int col = n0 + wc * 64 + ni * 16 + l15;
        ushort4 o;
        o.x = f2b(acc[mi][ni][0]);
        o.y = f2b(acc[mi][ni][1]);
        o.z = f2b(acc[mi][ni][2]);
        o.w = f2b(acc[mi][ni][3]);
        *(ushort4*)((u16*)outv + ((size_t)(nloc * 256 + col)) * 384 + ib) = o;
      }
    }
    return;
  }
#pragma unroll
  for (int mi = 0; mi < 4; ++mi) {
    int rbase = i0 + wr * 64 + mi * 16 + quad * 4;
#pragma unroll
    for (int ni = 0; ni < 4; ++ni) {
      int col = n0 + wc * 64 + ni * 16 + l15;
      float bv = bias ? b2f(bias[col]) : 0.f;
#pragma unroll
      for (int r = 0; r < 4; ++r) {
        float val = (acc[mi][ni][r] + bv) * alpha;
        if (mode == 2) {
          int i = rbase - nloc * 384 + r;  // residue index within L
          int h = col >> 5;                // head
          val *= sw[((size_t)(i * 8 + h)) * 256 + (n0sw + nloc)];
        }
        size_t idx = (ooff + (size_t)(rbase + r)) * 256 + col;
        if (mode == 1) {
          float gate = 1.f / (1.f + expf(-val));
          ((u16*)outv)[idx] = f2b(b2f(((u16*)outv)[idx]) * gate);
        } else if (f32out) {
          ((float*)outv)[idx] = val;
        } else {
          ((u16*)outv)[idx] = f2b(val);
        }
      }
    }
  }
}

// ---------------- SequenceWeight logits (chunked) ----------------
__global__ __launch_bounds__(256) void sw_logits_c(const u16* __restrict__ qsw, const u16* __restrict__ kswc,
                                                   float* __restrict__ swlog, int n0) {
  int nl = blockIdx.y;
  int t = blockIdx.x * 256 + threadIdx.x;
  int i = t >> 3, h = t & 7;
  const u16* kr = kswc + ((size_t)(nl * 384 + i)) * 256 + h * 32;
  const u16* qr = qsw + (size_t)i * 256 + h * 32;
  float dot = 0.f;
#pragma unroll
  for (int d8 = 0; d8 < 4; ++d8) {
    union { uint4 u; u16 us[8]; } ku, qu;
    ku.u = *(const uint4*)(kr + d8 * 8);
    qu.u = *(const uint4*)(qr + d8 * 8);
#pragma unroll
    for (int j = 0; j < 8; ++j) dot += b2f(ku.us[j]) * b2f(qu.us[j]);
  }
  swlog[(size_t)(i * 8 + h) * 256 + n0 + nl] = dot;
}

// ---------------- softmax over n (256) ----------------
__global__ __launch_bounds__(256) void sw_softmax(float* __restrict__ swlog) {
  __shared__ float red[4];
  float* p = swlog + (size_t)blockIdx.x * 256;
  int wave = threadIdx.x >> 6, lane = threadIdx.x & 63;
  float x = p[threadIdx.x];
  float m = wave_max(x);
  if (lane == 0) red[wave] = m;
  __syncthreads();
  float mx = fmaxf(fmaxf(red[0], red[1]), fmaxf(red[2], red[3]));
  __syncthreads();
  float e = expf(x - mx);
  float s = wave_sum(e);
  if (lane == 0) red[wave] = s;
  __syncthreads();
  float sum = red[0] + red[1] + red[2] + red[3];
  p[threadIdx.x] = e / sum;
}

// ---------------- pair LayerNorm + @wb -> attn bias ----------------
__global__ __launch_bounds__(256) void pair_bias(const void* __restrict__ pairv, const u16* __restrict__ g,
                                                 const u16* __restrict__ b, const u16* __restrict__ wb,
                                                 float* __restrict__ attn, const int* __restrict__ flagp) {
  int isf32 = *flagp;
  int wave = threadIdx.x >> 6, lane = threadIdx.x & 63;
  size_t row = (size_t)blockIdx.x * 4 + wave;
  float v0, v1;
  if (isf32) {
    const float* pf = (const float*)pairv + row * 128 + lane * 2;
    v0 = pf[0]; v1 = pf[1];
  } else {
    const u16* pr = (const u16*)pairv + row * 128 + lane * 2;
    v0 = b2f(pr[0]); v1 = b2f(pr[1]);
  }
  float s = wave_sum(v0 + v1);
  float s2 = wave_sum(v0 * v0 + v1 * v1);
  float mean = s * (1.f / 128.f);
  float var = s2 * (1.f / 128.f) - mean * mean;
  float inv = rsqrtf(var + 1e-5f);
  int c0 = lane * 2;
  v0 = (v0 - mean) * inv * b2f(g[c0]) + b2f(b[c0]);
  v1 = (v1 - mean) * inv * b2f(g[c0 + 1]) + b2f(b[c0 + 1]);
  float ph[8];
  const u16* w0 = wb + c0 * 8;
#pragma unroll
  for (int h = 0; h < 8; ++h) ph[h] = v0 * b2f(w0[h]) + v1 * b2f(w0[8 + h]);
#pragma unroll
  for (int m = 32; m >= 1; m >>= 1)
#pragma unroll
    for (int h = 0; h < 8; ++h) ph[h] += __shfl_xor(ph[h], m, 64);
  if (lane == 0) {
#pragma unroll
    for (int h = 0; h < 8; ++h) attn[(size_t)h * 147456 + row] = ph[h];
  }
}

// ---------------- QK chunk ----------------
__global__ __launch_bounds__(256) void qk_accum_c(const u16* __restrict__ qc, const u16* __restrict__ kc,
                                                  float* __restrict__ attn, int nlen) {
  int h = blockIdx.y;
  int i0 = (blockIdx.x % 3) * 128, j0 = (blockIdx.x / 3) * 128;
  int nb = blockIdx.z * nlen;
  int wave = threadIdx.x >> 6, lane = threadIdx.x & 63;
  int wr = wave >> 1, wc = wave & 1;
  int l15 = lane & 15, quad = lane >> 4;
  const f32x4 fz = {0.f, 0.f, 0.f, 0.f};
  f32x4 acc[4][4];
  for (int mi = 0; mi < 4; ++mi)
    for (int ni = 0; ni < 4; ++ni) acc[mi][ni] = fz;
  int arow = i0 + wr * 64 + l15;
  int brow = j0 + wc * 64 + l15;
  for (int n = nb; n < nb + nlen; ++n) {
    size_t base = (size_t)n * 384;
    const u16* ap = qc + (base + arow) * 256 + h * 32 + quad * 8;
    const u16* bp = kc + (base + brow) * 256 + h * 32 + quad * 8;
    bf16x8 a[4], b[4];
#pragma unroll
    for (int mi = 0; mi < 4; ++mi) a[mi] = load8bf(ap + mi * 16 * 256);
#pragma unroll
    for (int ni = 0; ni < 4; ++ni) b[ni] = load8bf(bp + ni * 16 * 256);
#pragma unroll
    for (int mi = 0; mi < 4; ++mi)
#pragma unroll
      for (int ni = 0; ni < 4; ++ni)
        acc[mi][ni] = __builtin_amdgcn_mfma_f32_16x16x32_bf16(a[mi], b[ni], acc[mi][ni], 0, 0, 0);
  }
#pragma unroll
  for (int mi = 0; mi < 4; ++mi)
#pragma unroll
    for (int ni = 0; ni < 4; ++ni) {
      int i = i0 + wr * 64 + mi * 16 + quad * 4;
      int j = j0 + wc * 64 + ni * 16 + l15;
#pragma unroll
      for (int r = 0; r < 4; ++r)
        atomicAdd(&attn[(size_t)h * 147456 + (size_t)(i + r) * 384 + j], acc[mi][ni][r]);
    }
}

// ---------------- softmax over j (384) -> bf16 ----------------
__global__ __launch_bounds__(384) void attn_softmax_k(const float* __restrict__ attn, u16* __restrict__ attn_bf) {
  __shared__ float red[6];
  size_t r = blockIdx.x;
  const float* p = attn + r * 384;
  int wave = threadIdx.x >> 6, lane = threadIdx.x & 63;
  float x = p[threadIdx.x];
  float m = wave_max(x);
  if (lane == 0) red[wave] = m;
  __syncthreads();
  float mx = red[0];
#pragma unroll
  for (int i = 1; i < 6; ++i) mx = fmaxf(mx, red[i]);
  __syncthreads();
  float e = expf(x - mx);
  float s = wave_sum(e);
  if (lane == 0) red[wave] = s;
  __syncthreads();
  float sum = 0.f;
#pragma unroll
  for (int i = 0; i < 6; ++i) sum += red[i];
  attn_bf[r * 384 + threadIdx.x] = f2b(e / sum);
}

// ---------------- PV as batched GEMM: per h, O = attn[h] (384x384) @ V (384 x NC*32) ----------------
// B^T is vt: row (nl*256 + h*32 + d) holds 384 j-contiguous values.
__global__ __launch_bounds__(256) void pv_gemm(const u16* __restrict__ attn_bf, const u16* __restrict__ vt,
                                               u16* __restrict__ oc) {
  int h = blockIdx.z;
  int i0 = blockIdx.x * 128;  // over i = 384
  int c0 = blockIdx.y * 128;  // over cols = NC*32 (n*32+d)
  int wave = threadIdx.x >> 6, lane = threadIdx.x & 63;
  int wr = wave >> 1, wc = wave & 1;
  int l15 = lane & 15, quad = lane >> 4;
  const f32x4 fz = {0.f, 0.f, 0.f, 0.f};
  f32x4 acc[4][4];
  for (int mi = 0; mi < 4; ++mi)
    for (int ni = 0; ni < 4; ++ni) acc[mi][ni] = fz;
  int arow = i0 + wr * 64 + l15;
  const u16* ap = attn_bf + ((size_t)(h * 384 + arow)) * 384 + quad * 8;
  const u16* bp[4];
#pragma unroll
  for (int ni = 0; ni < 4; ++ni) {
    int col = c0 + wc * 64 + ni * 16 + l15;
    bp[ni] = vt + ((size_t)((col >> 5) * 256 + h * 32 + (col & 31))) * 384 + quad * 8;
  }
  for (int k0 = 0; k0 < 384; k0 += 32) {
    bf16x8 a[4], b[4];
#pragma unroll
    for (int mi = 0; mi < 4; ++mi) a[mi] = load8bf(ap + mi * 16 * 384 + k0);
#pragma unroll
    for (int ni = 0; ni < 4; ++ni) b[ni] = load8bf(bp[ni] + k0);
#pragma unroll
    for (int mi = 0; mi < 4; ++mi)
#pragma unroll
      for (int ni = 0; ni < 4; ++ni)
        acc[mi][ni] = __builtin_amdgcn_mfma_f32_16x16x32_bf16(a[mi], b[ni], acc[mi][ni], 0, 0, 0);
  }
#pragma unroll
  for (int mi = 0; mi < 4; ++mi) {
    int ib = i0 + wr * 64 + mi * 16 + quad * 4;
#pragma unroll
    for (int ni = 0; ni < 4; ++ni) {
      int col = c0 + wc * 64 + ni * 16 + l15;
      int nl = col >> 5, d = col & 31;
#pragma unroll
      for (int r = 0; r < 4; ++r)
        oc[((size_t)(nl * 384 + ib + r)) * 256 + h * 32 + d] = f2b(acc[mi][ni][r]);
    }
  }
}

extern "C" void kernel_launch(void* const* d_in, const int* in_sizes, int n_in,
                              void* d_out, int out_size, void* d_ws, size_t ws_size,
                              hipStream_t stream) {
  const void* msa = d_in[0];
  const void* pair = d_in[1];
  const void* ln_msa_g = d_in[2];
  const void* ln_msa_b = d_in[3];
  const void* ln_pair_g = d_in[4];
  const void* ln_pair_b = d_in[5];
  const void* sw_wq = d_in[6];
  const void* sw_bq = d_in[7];
  const void* sw_wk = d_in[8];
  const void* sw_bk = d_in[9];
  const void* wq = d_in[10];
  const void* wk = d_in[11];
  const void* wv = d_in[12];
  const void* wb = d_in[13];
  const void* wg = d_in[14];
  const void* bg = d_in[15];
  const void* wo = d_in[16];
  const void* bo = d_in[17];

  char* ws = (char*)d_ws;
  int* flag = (int*)ws;                   //      256 B @ 0
  float* swlog = (float*)(ws + 256);      //  3145728 B
  float* attnf = (float*)(ws + 3145984);  //  4718592 B
  u16* wT = (u16*)(ws + 7864576);         //   917504 B
  u16* qswb = (u16*)(ws + 8782080);       //   196608 B
  u16* attnbf = (u16*)(ws + 8978688);     //  2359296 B
  u16* smallv = (u16*)(ws + 11337984);    //     5632 B
  u16* mbf = (u16*)(ws + 11343616);       // 50331648 B  (LN(msa) in bf16)
  const size_t SMALLS = 61675264ull;
  u16* c_lng = smallv + 0;
  u16* c_lnb = smallv + 256;
  u16* c_lpg = smallv + 512;
  u16* c_lpb = smallv + 640;
  u16* c_sbq = smallv + 768;
  u16* c_sbk = smallv + 1024;
  u16* c_bg = smallv + 1280;
  u16* c_bo = smallv + 1536;
  u16* c_wb = smallv + 1792;

  int NC = 256;
  while (NC > 8 && SMALLS + 3ull * (size_t)NC * 196608ull > ws_size) NC >>= 1;
  const size_t CBsz = (size_t)NC * 196608ull;
  u16* CB1 = (u16*)(ws + SMALLS);
  u16* CB2 = (u16*)(ws + SMALLS + CBsz);
  u16* CB3 = (u16*)(ws + SMALLS + 2 * CBsz);
  const int nchunks = 256 / NC;
  const int nlen = (NC < 32) ? NC : 32;  // z-split: balance occupancy vs atomic traffic

  const float isd = 0.17677669529663687f;  // 1/sqrt(32)

  detect_dtype<<<1, 256, 0, stream>>>((const u16*)msa, flag);

  SmallCvt sc;
  sc.src[0] = ln_msa_g;  sc.n[0] = 256;  sc.off[0] = 0;
  sc.src[1] = ln_msa_b;  sc.n[1] = 256;  sc.off[1] = 256;
  sc.src[2] = ln_pair_g; sc.n[2] = 128;  sc.off[2] = 512;
  sc.src[3] = ln_pair_b; sc.n[3] = 128;  sc.off[3] = 640;
  sc.src[4] = sw_bq;     sc.n[4] = 256;  sc.off[4] = 768;
  sc.src[5] = sw_bk;     sc.n[5] = 256;  sc.off[5] = 1024;
  sc.src[6] = bg;        sc.n[6] = 256;  sc.off[6] = 1280;
  sc.src[7] = bo;        sc.n[7] = 256;  sc.off[7] = 1536;
  sc.src[8] = wb;        sc.n[8] = 1024; sc.off[8] = 1792;
  cvt_small<<<9, 256, 0, stream>>>(sc, smallv, flag);

  TransArgs ta;
  ta.src[0] = sw_wq; ta.src[1] = sw_wk; ta.src[2] = wq; ta.src[3] = wk;
  ta.src[4] = wv;    ta.src[5] = wg;    ta.src[6] = wo;
  for (int i = 0; i < 7; ++i) ta.dst[i] = wT + i * 65536;
  transpose_w<<<dim3(8, 8, 7), 256, 0, stream>>>(ta, flag);

  // LN(msa) -> bf16 once; all projections consume this.
  ln_msa_k<<<24576, 256, 0, stream>>>(msa, c_lng, c_lnb, mbf, flag);

  // qsw = (LN(msa)[:,0] @ sw_wq + sw_bq) * isd
  gemmA<<<dim3(3, 2), 256, 0, stream>>>(mbf, 0, wT + 0 * 65536, c_sbq,
                                        qswb, 0, 0, isd, nullptr, 0, flag, 0,
                                        nullptr, nullptr, 0, 0.f);

  for (int c = 0; c < nchunks; ++c) {
    size_t R = (size_t)c * NC * 384;
    gemmA<<<dim3(3 * NC, 2), 256, 0, stream>>>(mbf, R, wT + 1 * 65536, c_sbk,
                                               CB1, 0, 0, 1.f, nullptr, 0, flag, 0,
                                               nullptr, nullptr, 0, 0.f);
    sw_logits_c<<<dim3(12, NC), 256, 0, stream>>>(qswb, CB1, swlog, c * NC);
  }
  sw_softmax<<<3072, 256, 0, stream>>>(swlog);

  pair_bias<<<36864, 256, 0, stream>>>(pair, c_lpg, c_lpb, c_wb, attnf, flag);
  for (int c = 0; c < nchunks; ++c) {
    size_t R = (size_t)c * NC * 384;
    // fused: q = LN(msa)@wq (mode 2, seq-weight in epilogue) -> CB1
    //        k = LN(msa)@wk * isd                             -> CB2
    gemmA<<<dim3(3 * NC, 4), 256, 0, stream>>>(mbf, R, wT + 2 * 65536, nullptr,
                                               CB1, 0, 2, 1.f, swlog, c * NC, flag, 0,
                                               wT + 3 * 65536, CB2, 0, isd);
    qk_accum_c<<<dim3(9, 8, NC / nlen), 256, 0, stream>>>(CB1, CB2, attnf, nlen);
  }
  attn_softmax_k<<<3072, 384, 0, stream>>>(attnf, attnbf);

  for (int c = 0; c < nchunks; ++c) {
    size_t R = (size_t)c * NC * 384;
    // v = LN(msa) @ wv, written directly in vt (transposed) layout via mode 3
    gemmA<<<dim3(3 * NC, 2), 256, 0, stream>>>(mbf, R, wT + 4 * 65536, nullptr,
                                               CB2, 0, 3, 1.f, nullptr, 0, flag, 0,
                                               nullptr, nullptr, 0, 0.f);
    pv_gemm<<<dim3(3, NC / 4, 8), 256, 0, stream>>>(attnbf, CB2, CB3);
    gemmA<<<dim3(3 * NC, 2), 256, 0, stream>>>(mbf, R, wT + 5 * 65536, c_bg,
                                               CB3, 0, 1, 1.f, nullptr, 0, flag, 0,
                                               nullptr, nullptr, 0, 0.f);
    gemmA<<<dim3(3 * NC, 2), 256, 0, stream>>>(CB3, 0, wT + 6 * 65536, c_bo,
                                               d_out, R, 0, 1.f, nullptr, 0, flag, 1,
                                               nullptr, nullptr, 0, 0.f);
  }
}

// Round 5
// 840.786 us; speedup vs baseline: 1.2261x; 1.0297x over previous
//
#include <hip/hip_runtime.h>
#include <math.h>

typedef unsigned short u16;
typedef __bf16 bf16x8 __attribute__((ext_vector_type(8)));
typedef float f32x4 __attribute__((ext_vector_type(4)));

#define DEV static __device__ __forceinline__

DEV float b2f(u16 u) { union { unsigned int i; float f; } v; v.i = ((unsigned int)u) << 16; return v.f; }
DEV u16 f2b(float f) {
  union { float f; unsigned int i; } v; v.f = f;
  unsigned int x = v.i;
  unsigned int r = (x + 0x7fffu + ((x >> 16) & 1u)) >> 16;
  return (u16)r;
}
DEV bf16x8 load8bf(const u16* p) {
  union { uint4 u; bf16x8 b; } t;
  t.u = *(const uint4*)p;
  return t.b;
}
// async global->LDS, 16 bytes per lane (dest must be wave-uniform base + lane*16)
DEV void gl_lds16(const u16* g, u16* l) {
  __builtin_amdgcn_global_load_lds((const __attribute__((address_space(1))) unsigned int*)g,
                                   (__attribute__((address_space(3))) unsigned int*)l, 16, 0, 0);
}
DEV float wave_sum(float x) {
  for (int m = 32; m >= 1; m >>= 1) x += __shfl_xor(x, m, 64);
  return x;
}
DEV float wave_max(float x) {
  for (int m = 32; m >= 1; m >>= 1) x = fmaxf(x, __shfl_xor(x, m, 64));
  return x;
}

// ---------------- dtype sniffer ----------------
__global__ __launch_bounds__(256) void detect_dtype(const u16* __restrict__ probe, int* __restrict__ flag) {
  __shared__ float red[4];
  int wave = threadIdx.x >> 6, lane = threadIdx.x & 63;
  float v = fabsf(b2f(probe[threadIdx.x]));
  v = wave_max(v);
  if (lane == 0) red[wave] = v;
  __syncthreads();
  if (threadIdx.x == 0) {
    float m = fmaxf(fmaxf(red[0], red[1]), fmaxf(red[2], red[3]));
    *flag = (m > 1e10f) ? 1 : 0;  // 1 => inputs are float32
  }
}

// ---------------- convert 9 small vectors to canonical bf16 ----------------
struct SmallCvt {
  const void* src[9];
  int n[9];
  int off[9];
};
__global__ __launch_bounds__(256) void cvt_small(SmallCvt s, u16* __restrict__ dst, const int* __restrict__ flagp) {
  int isf32 = *flagp;
  int a = blockIdx.x;
  const void* sp = s.src[a];
  for (int i = threadIdx.x; i < s.n[a]; i += 256) {
    float v = isf32 ? ((const float*)sp)[i] : b2f(((const u16*)sp)[i]);
    dst[s.off[a] + i] = f2b(v);
  }
}

// ---------------- fused LayerNorm(msa) -> canonical bf16 ----------------
__global__ __launch_bounds__(256) void ln_msa_k(const void* __restrict__ xv, const u16* __restrict__ g,
                                                const u16* __restrict__ b, u16* __restrict__ out,
                                                const int* __restrict__ flagp) {
  int isf32 = *flagp;
  int wave = threadIdx.x >> 6, lane = threadIdx.x & 63;
  size_t row = (size_t)blockIdx.x * 4 + wave;
  float f0, f1, f2, f3;
  if (isf32) {
    float4 v = *(const float4*)((const float*)xv + row * 256 + lane * 4);
    f0 = v.x; f1 = v.y; f2 = v.z; f3 = v.w;
  } else {
    ushort4 v = *(const ushort4*)((const u16*)xv + row * 256 + lane * 4);
    f0 = b2f(v.x); f1 = b2f(v.y); f2 = b2f(v.z); f3 = b2f(v.w);
  }
  float s = wave_sum(f0 + f1 + f2 + f3);
  float s2 = wave_sum(f0 * f0 + f1 * f1 + f2 * f2 + f3 * f3);
  float mean = s * (1.f / 256.f);
  float inv = rsqrtf(s2 * (1.f / 256.f) - mean * mean + 1e-5f);
  int c0 = lane * 4;
  ushort4 gv = *(const ushort4*)(g + c0);
  ushort4 bv = *(const ushort4*)(b + c0);
  ushort4 o;
  o.x = f2b((f0 - mean) * inv * b2f(gv.x) + b2f(bv.x));
  o.y = f2b((f1 - mean) * inv * b2f(gv.y) + b2f(bv.y));
  o.z = f2b((f2 - mean) * inv * b2f(gv.z) + b2f(bv.z));
  o.w = f2b((f3 - mean) * inv * b2f(gv.w) + b2f(bv.w));
  *(ushort4*)(out + row * 256 + c0) = o;
}

// ---------------- transpose seven 256x256 weight matrices -> bf16 ----------------
struct TransArgs {
  const void* src[7];
  u16* dst[7];
};
__global__ __launch_bounds__(256) void transpose_w(TransArgs t, const int* __restrict__ flagp) {
  __shared__ float tile[32][33];
  int isf32 = *flagp;
  int m = blockIdx.z;
  const void* s = t.src[m];
  u16* d = t.dst[m];
  int bx = blockIdx.x * 32, by = blockIdx.y * 32;
  int c = threadIdx.x & 31, r0 = threadIdx.x >> 5;
  for (int rr = r0; rr < 32; rr += 8) {
    int idx = (by + rr) * 256 + bx + c;
    tile[rr][c] = isf32 ? ((const float*)s)[idx] : b2f(((const u16*)s)[idx]);
  }
  __syncthreads();
  for (int rr = r0; rr < 32; rr += 8) d[(bx + rr) * 256 + by + c] = f2b(tile[c][rr]);
}

// ---------------- GEMM: out[rows,256] = f((A @ W + bias) * alpha) ----------------
// LDS-staged (global_load_lds w16) 128x128 tile, BK=64, XOR-swizzled LDS layout.
// 1D grid, XCD-aware decode: the Y blocks sharing an A-tile are consecutive
// slots on one XCD so the A-tile is fetched once per XCD L2 (falls back to
// linear decode when nbx % 8 != 0).
// mode: 0 = store, 1 = sigmoid-gate RMW, 2 = multiply by seq_weight then store,
//       3 = store transposed into vt layout (for the v projection).
// If WT2 != nullptr, Y = 4: by<2 computes WT->outv, by>=2 computes WT2->out2.
__global__ __launch_bounds__(256) void gemmA(const u16* __restrict__ A, size_t aoff,
                                             const u16* __restrict__ WT, const u16* __restrict__ bias,
                                             void* __restrict__ outv, size_t ooff, int mode, float alpha,
                                             const float* __restrict__ sw, int n0sw,
                                             const int* __restrict__ flagp, int out_flag,
                                             const u16* __restrict__ WT2, void* __restrict__ out2,
                                             int mode_b, float alpha_b, int nbx) {
  __shared__ u16 As[128 * 64];
  __shared__ u16 Bs[128 * 64];
  int isf32 = *flagp;
  int Y = WT2 ? 4 : 2;
  int id = blockIdx.x;
  int bx, by;
  if ((nbx & 7) == 0) {
    int xcd = id & 7, slot = id >> 3;
    bx = xcd * (nbx >> 3) + slot / Y;
    by = slot % Y;
  } else {
    bx = id % nbx;
    by = id / nbx;
  }
  int n0;
  if (WT2) {
    if (by >> 1) { WT = WT2; outv = out2; mode = mode_b; alpha = alpha_b; bias = nullptr; }
    n0 = (by & 1) * 128;
  } else {
    n0 = by * 128;
  }
  int i0 = bx * 128;
  int t = threadIdx.x;
  int wave = t >> 6, lane = t & 63;
  int wr = wave >> 1, wc = wave & 1;
  int l15 = lane & 15, quad = lane >> 4;
  const f32x4 fz = {0.f, 0.f, 0.f, 0.f};
  f32x4 acc[4][4];
  for (int mi = 0; mi < 4; ++mi)
    for (int ni = 0; ni < 4; ++ni) acc[mi][ni] = fz;
  // staging: thread t, pass p stages 16B; LDS row = t/8 + p*32, swizzled source col:
  int srow = t >> 3;
  int scol = ((t & 7) ^ (srow & 7)) * 8;  // pre-swizzled global col so LDS lands swizzled
  const u16* ga = A + (aoff + (size_t)(i0 + srow)) * 256 + scol;
  const u16* gb = WT + ((size_t)(n0 + srow)) * 256 + scol;
  u16* la = As + t * 8;
  u16* lb = Bs + t * 8;
  for (int k0 = 0; k0 < 256; k0 += 64) {
    __syncthreads();  // protect LDS from readers of previous K-step
#pragma unroll
    for (int p = 0; p < 4; ++p) {
      gl_lds16(ga + (size_t)p * 32 * 256 + k0, la + p * 2048);
      gl_lds16(gb + (size_t)p * 32 * 256 + k0, lb + p * 2048);
    }
    __syncthreads();  // drains vmcnt, publishes LDS
#pragma unroll
    for (int kk = 0; kk < 2; ++kk) {
      bf16x8 a[4], b[4];
      int kc = kk * 32 + quad * 8;
#pragma unroll
      for (int mi = 0; mi < 4; ++mi) {
        int row = wr * 64 + mi * 16 + l15;
        a[mi] = load8bf(As + row * 64 + (kc ^ ((row & 7) << 3)));
      }
#pragma unroll
      for (int ni = 0; ni < 4; ++ni) {
        int row = wc * 64 + ni * 16 + l15;
        b[ni] = load8bf(Bs + row * 64 + (kc ^ ((row & 7) << 3)));
      }
#pragma unroll
      for (int mi = 0; mi < 4; ++mi)
#pragma unroll
        for (int ni = 0; ni < 4; ++ni)
          acc[mi][ni] = __builtin_amdgcn_mfma_f32_16x16x32_bf16(a[mi], b[ni], acc[mi][ni], 0, 0, 0);
    }
  }
  int f32out = out_flag && isf32;
  int nloc = bx / 3;  // local MSA-row index within chunk (each 384-row slab = 3 x-blocks)
  if (mode == 3) {
    // write v transposed: vt[(nloc*256 + col)][i] ; 4 acc rows are 4 consecutive i
#pragma unroll
    for (int mi = 0; mi < 4; ++mi) {
      int ib = i0 + wr * 64 + mi * 16 + quad * 4 - nloc * 384;
#pragma unroll
      for (int ni = 0; ni < 4; ++ni) {
        int col = n0 + wc * 64 + ni * 16 + l15;
        ushort4 o;
        o.x = f2b(acc[mi][ni][0]);
        o.y = f2b(acc[mi][ni][1]);
        o.z = f2b(acc[mi][ni][2]);
        o.w = f2b(acc[mi][ni][3]);
        *(ushort4*)((u16*)outv + ((size_t)(nloc * 256 + col)) * 384 + ib) = o;
      }
    }
    return;
  }
#pragma unroll
  for (int mi = 0; mi < 4; ++mi) {
    int rbase = i0 + wr * 64 + mi * 16 + quad * 4;
#pragma unroll
    for (int ni = 0; ni < 4; ++ni) {
      int col = n0 + wc * 64 + ni * 16 + l15;
      float bv = bias ? b2f(bias[col]) : 0.f;
#pragma unroll
      for (int r = 0; r < 4; ++r) {
        float val = (acc[mi][ni][r] + bv) * alpha;
        if (mode == 2) {
          int i = rbase - nloc * 384 + r;  // residue index within L
          int h = col >> 5;                // head
          val *= sw[((size_t)(i * 8 + h)) * 256 + (n0sw + nloc)];
        }
        size_t idx = (ooff + (size_t)(rbase + r)) * 256 + col;
        if (mode == 1) {
          float gate = 1.f / (1.f + expf(-val));
          ((u16*)outv)[idx] = f2b(b2f(((u16*)outv)[idx]) * gate);
        } else if (f32out) {
          ((float*)outv)[idx] = val;
        } else {
          ((u16*)outv)[idx] = f2b(val);
        }
      }
    }
  }
}

// ---------------- SequenceWeight logits (chunked) ----------------
__global__ __launch_bounds__(256) void sw_logits_c(const u16* __restrict__ qsw, const u16* __restrict__ kswc,
                                                   float* __restrict__ swlog, int n0) {
  int nl = blockIdx.y;
  int t = blockIdx.x * 256 + threadIdx.x;
  int i = t >> 3, h = t & 7;
  const u16* kr = kswc + ((size_t)(nl * 384 + i)) * 256 + h * 32;
  const u16* qr = qsw + (size_t)i * 256 + h * 32;
  float dot = 0.f;
#pragma unroll
  for (int d8 = 0; d8 < 4; ++d8) {
    union { uint4 u; u16 us[8]; } ku, qu;
    ku.u = *(const uint4*)(kr + d8 * 8);
    qu.u = *(const uint4*)(qr + d8 * 8);
#pragma unroll
    for (int j = 0; j < 8; ++j) dot += b2f(ku.us[j]) * b2f(qu.us[j]);
  }
  swlog[(size_t)(i * 8 + h) * 256 + n0 + nl] = dot;
}

// ---------------- softmax over n (256) ----------------
__global__ __launch_bounds__(256) void sw_softmax(float* __restrict__ swlog) {
  __shared__ float red[4];
  float* p = swlog + (size_t)blockIdx.x * 256;
  int wave = threadIdx.x >> 6, lane = threadIdx.x & 63;
  float x = p[threadIdx.x];
  float m = wave_max(x);
  if (lane == 0) red[wave] = m;
  __syncthreads();
  float mx = fmaxf(fmaxf(red[0], red[1]), fmaxf(red[2], red[3]));
  __syncthreads();
  float e = expf(x - mx);
  float s = wave_sum(e);
  if (lane == 0) red[wave] = s;
  __syncthreads();
  float sum = red[0] + red[1] + red[2] + red[3];
  p[threadIdx.x] = e / sum;
}

// ---------------- pair LayerNorm + @wb -> attn bias ----------------
__global__ __launch_bounds__(256) void pair_bias(const void* __restrict__ pairv, const u16* __restrict__ g,
                                                 const u16* __restrict__ b, const u16* __restrict__ wb,
                                                 float* __restrict__ attn, const int* __restrict__ flagp) {
  int isf32 = *flagp;
  int wave = threadIdx.x >> 6, lane = threadIdx.x & 63;
  size_t row = (size_t)blockIdx.x * 4 + wave;
  float v0, v1;
  if (isf32) {
    const float* pf = (const float*)pairv + row * 128 + lane * 2;
    v0 = pf[0]; v1 = pf[1];
  } else {
    const u16* pr = (const u16*)pairv + row * 128 + lane * 2;
    v0 = b2f(pr[0]); v1 = b2f(pr[1]);
  }
  float s = wave_sum(v0 + v1);
  float s2 = wave_sum(v0 * v0 + v1 * v1);
  float mean = s * (1.f / 128.f);
  float var = s2 * (1.f / 128.f) - mean * mean;
  float inv = rsqrtf(var + 1e-5f);
  int c0 = lane * 2;
  v0 = (v0 - mean) * inv * b2f(g[c0]) + b2f(b[c0]);
  v1 = (v1 - mean) * inv * b2f(g[c0 + 1]) + b2f(b[c0 + 1]);
  float ph[8];
  const u16* w0 = wb + c0 * 8;
#pragma unroll
  for (int h = 0; h < 8; ++h) ph[h] = v0 * b2f(w0[h]) + v1 * b2f(w0[8 + h]);
#pragma unroll
  for (int m = 32; m >= 1; m >>= 1)
#pragma unroll
    for (int h = 0; h < 8; ++h) ph[h] += __shfl_xor(ph[h], m, 64);
  if (lane == 0) {
#pragma unroll
    for (int h = 0; h < 8; ++h) attn[(size_t)h * 147456 + row] = ph[h];
  }
}

// ---------------- QK chunk ----------------
// 1D grid of 72*Z blocks (Z = n-partitions). XCD-aware decode: the 9 (i,j)
// tiles of one (h, z) combo are consecutive slots on one XCD, so their shared
// q/k rows (~1.5 MB) live in that XCD's L2 instead of being re-fetched 3x.
__global__ __launch_bounds__(256) void qk_accum_c(const u16* __restrict__ qc, const u16* __restrict__ kc,
                                                  float* __restrict__ attn, int nlen) {
  int id = blockIdx.x;
  int Z = gridDim.x / 72;
  int xcd = id & 7, slot = id >> 3;
  int tile = slot % 9;
  int combo = xcd * Z + slot / 9;
  int h = combo % 8;
  int z = combo / 8;
  int i0 = (tile % 3) * 128, j0 = (tile / 3) * 128;
  int nb = z * nlen;
  int wave = threadIdx.x >> 6, lane = threadIdx.x & 63;
  int wr = wave >> 1, wc = wave & 1;
  int l15 = lane & 15, quad = lane >> 4;
  const f32x4 fz = {0.f, 0.f, 0.f, 0.f};
  f32x4 acc[4][4];
  for (int mi = 0; mi < 4; ++mi)
    for (int ni = 0; ni < 4; ++ni) acc[mi][ni] = fz;
  int arow = i0 + wr * 64 + l15;
  int brow = j0 + wc * 64 + l15;
  for (int n = nb; n < nb + nlen; ++n) {
    size_t base = (size_t)n * 384;
    const u16* ap = qc + (base + arow) * 256 + h * 32 + quad * 8;
    const u16* bp = kc + (base + brow) * 256 + h * 32 + quad * 8;
    bf16x8 a[4], b[4];
#pragma unroll
    for (int mi = 0; mi < 4; ++mi) a[mi] = load8bf(ap + mi * 16 * 256);
#pragma unroll
    for (int ni = 0; ni < 4; ++ni) b[ni] = load8bf(bp + ni * 16 * 256);
#pragma unroll
    for (int mi = 0; mi < 4; ++mi)
#pragma unroll
      for (int ni = 0; ni < 4; ++ni)
        acc[mi][ni] = __builtin_amdgcn_mfma_f32_16x16x32_bf16(a[mi], b[ni], acc[mi][ni], 0, 0, 0);
  }
#pragma unroll
  for (int mi = 0; mi < 4; ++mi)
#pragma unroll
    for (int ni = 0; ni < 4; ++ni) {
      int i = i0 + wr * 64 + mi * 16 + quad * 4;
      int j = j0 + wc * 64 + ni * 16 + l15;
#pragma unroll
      for (int r = 0; r < 4; ++r)
        atomicAdd(&attn[(size_t)h * 147456 + (size_t)(i + r) * 384 + j], acc[mi][ni][r]);
    }
}

// ---------------- softmax over j (384) -> bf16 ----------------
__global__ __launch_bounds__(384) void attn_softmax_k(const float* __restrict__ attn, u16* __restrict__ attn_bf) {
  __shared__ float red[6];
  size_t r = blockIdx.x;
  const float* p = attn + r * 384;
  int wave = threadIdx.x >> 6, lane = threadIdx.x & 63;
  float x = p[threadIdx.x];
  float m = wave_max(x);
  if (lane == 0) red[wave] = m;
  __syncthreads();
  float mx = red[0];
#pragma unroll
  for (int i = 1; i < 6; ++i) mx = fmaxf(mx, red[i]);
  __syncthreads();
  float e = expf(x - mx);
  float s = wave_sum(e);
  if (lane == 0) red[wave] = s;
  __syncthreads();
  float sum = 0.f;
#pragma unroll
  for (int i = 0; i < 6; ++i) sum += red[i];
  attn_bf[r * 384 + threadIdx.x] = f2b(e / sum);
}

// ---------------- PV as batched GEMM: per h, O = attn[h] (384x384) @ V (384 x NC*32) ----------------
// B^T is vt: row (nl*256 + h*32 + d) holds 384 j-contiguous values.
__global__ __launch_bounds__(256) void pv_gemm(const u16* __restrict__ attn_bf, const u16* __restrict__ vt,
                                               u16* __restrict__ oc) {
  int h = blockIdx.z;
  int i0 = blockIdx.x * 128;  // over i = 384
  int c0 = blockIdx.y * 128;  // over cols = NC*32 (n*32+d)
  int wave = threadIdx.x >> 6, lane = threadIdx.x & 63;
  int wr = wave >> 1, wc = wave & 1;
  int l15 = lane & 15, quad = lane >> 4;
  const f32x4 fz = {0.f, 0.f, 0.f, 0.f};
  f32x4 acc[4][4];
  for (int mi = 0; mi < 4; ++mi)
    for (int ni = 0; ni < 4; ++ni) acc[mi][ni] = fz;
  int arow = i0 + wr * 64 + l15;
  const u16* ap = attn_bf + ((size_t)(h * 384 + arow)) * 384 + quad * 8;
  const u16* bp[4];
#pragma unroll
  for (int ni = 0; ni < 4; ++ni) {
    int col = c0 + wc * 64 + ni * 16 + l15;
    bp[ni] = vt + ((size_t)((col >> 5) * 256 + h * 32 + (col & 31))) * 384 + quad * 8;
  }
  for (int k0 = 0; k0 < 384; k0 += 32) {
    bf16x8 a[4], b[4];
#pragma unroll
    for (int mi = 0; mi < 4; ++mi) a[mi] = load8bf(ap + mi * 16 * 384 + k0);
#pragma unroll
    for (int ni = 0; ni < 4; ++ni) b[ni] = load8bf(bp[ni] + k0);
#pragma unroll
    for (int mi = 0; mi < 4; ++mi)
#pragma unroll
      for (int ni = 0; ni < 4; ++ni)
        acc[mi][ni] = __builtin_amdgcn_mfma_f32_16x16x32_bf16(a[mi], b[ni], acc[mi][ni], 0, 0, 0);
  }
#pragma unroll
  for (int mi = 0; mi < 4; ++mi) {
    int ib = i0 + wr * 64 + mi * 16 + quad * 4;
#pragma unroll
    for (int ni = 0; ni < 4; ++ni) {
      int col = c0 + wc * 64 + ni * 16 + l15;
      int nl = col >> 5, d = col & 31;
#pragma unroll
      for (int r = 0; r < 4; ++r)
        oc[((size_t)(nl * 384 + ib + r)) * 256 + h * 32 + d] = f2b(acc[mi][ni][r]);
    }
  }
}

extern "C" void kernel_launch(void* const* d_in, const int* in_sizes, int n_in,
                              void* d_out, int out_size, void* d_ws, size_t ws_size,
                              hipStream_t stream) {
  const void* msa = d_in[0];
  const void* pair = d_in[1];
  const void* ln_msa_g = d_in[2];
  const void* ln_msa_b = d_in[3];
  const void* ln_pair_g = d_in[4];
  const void* ln_pair_b = d_in[5];
  const void* sw_wq = d_in[6];
  const void* sw_bq = d_in[7];
  const void* sw_wk = d_in[8];
  const void* sw_bk = d_in[9];
  const void* wq = d_in[10];
  const void* wk = d_in[11];
  const void* wv = d_in[12];
  const void* wb = d_in[13];
  const void* wg = d_in[14];
  const void* bg = d_in[15];
  const void* wo = d_in[16];
  const void* bo = d_in[17];

  char* ws = (char*)d_ws;
  int* flag = (int*)ws;                   //      256 B @ 0
  float* swlog = (float*)(ws + 256);      //  3145728 B
  float* attnf = (float*)(ws + 3145984);  //  4718592 B
  u16* wT = (u16*)(ws + 7864576);         //   917504 B
  u16* qswb = (u16*)(ws + 8782080);       //   196608 B
  u16* attnbf = (u16*)(ws + 8978688);     //  2359296 B
  u16* smallv = (u16*)(ws + 11337984);    //     5632 B
  u16* mbf = (u16*)(ws + 11343616);       // 50331648 B  (LN(msa) in bf16)
  const size_t SMALLS = 61675264ull;
  u16* c_lng = smallv + 0;
  u16* c_lnb = smallv + 256;
  u16* c_lpg = smallv + 512;
  u16* c_lpb = smallv + 640;
  u16* c_sbq = smallv + 768;
  u16* c_sbk = smallv + 1024;
  u16* c_bg = smallv + 1280;
  u16* c_bo = smallv + 1536;
  u16* c_wb = smallv + 1792;

  int NC = 256;
  while (NC > 8 && SMALLS + 3ull * (size_t)NC * 196608ull > ws_size) NC >>= 1;
  const size_t CBsz = (size_t)NC * 196608ull;
  u16* CB1 = (u16*)(ws + SMALLS);
  u16* CB2 = (u16*)(ws + SMALLS + CBsz);
  u16* CB3 = (u16*)(ws + SMALLS + 2 * CBsz);
  const int nchunks = 256 / NC;
  const int nlen = (NC < 32) ? NC : 32;  // z-split: balance occupancy vs atomic traffic

  const float isd = 0.17677669529663687f;  // 1/sqrt(32)

  detect_dtype<<<1, 256, 0, stream>>>((const u16*)msa, flag);

  SmallCvt sc;
  sc.src[0] = ln_msa_g;  sc.n[0] = 256;  sc.off[0] = 0;
  sc.src[1] = ln_msa_b;  sc.n[1] = 256;  sc.off[1] = 256;
  sc.src[2] = ln_pair_g; sc.n[2] = 128;  sc.off[2] = 512;
  sc.src[3] = ln_pair_b; sc.n[3] = 128;  sc.off[3] = 640;
  sc.src[4] = sw_bq;     sc.n[4] = 256;  sc.off[4] = 768;
  sc.src[5] = sw_bk;     sc.n[5] = 256;  sc.off[5] = 1024;
  sc.src[6] = bg;        sc.n[6] = 256;  sc.off[6] = 1280;
  sc.src[7] = bo;        sc.n[7] = 256;  sc.off[7] = 1536;
  sc.src[8] = wb;        sc.n[8] = 1024; sc.off[8] = 1792;
  cvt_small<<<9, 256, 0, stream>>>(sc, smallv, flag);

  TransArgs ta;
  ta.src[0] = sw_wq; ta.src[1] = sw_wk; ta.src[2] = wq; ta.src[3] = wk;
  ta.src[4] = wv;    ta.src[5] = wg;    ta.src[6] = wo;
  for (int i = 0; i < 7; ++i) ta.dst[i] = wT + i * 65536;
  transpose_w<<<dim3(8, 8, 7), 256, 0, stream>>>(ta, flag);

  // LN(msa) -> bf16 once; all projections consume this.
  ln_msa_k<<<24576, 256, 0, stream>>>(msa, c_lng, c_lnb, mbf, flag);

  // qsw = (LN(msa)[:,0] @ sw_wq + sw_bq) * isd   (nbx=3 -> linear decode)
  gemmA<<<dim3(6), 256, 0, stream>>>(mbf, 0, wT + 0 * 65536, c_sbq,
                                     qswb, 0, 0, isd, nullptr, 0, flag, 0,
                                     nullptr, nullptr, 0, 0.f, 3);

  for (int c = 0; c < nchunks; ++c) {
    size_t R = (size_t)c * NC * 384;
    gemmA<<<dim3(3 * NC * 2), 256, 0, stream>>>(mbf, R, wT + 1 * 65536, c_sbk,
                                                CB1, 0, 0, 1.f, nullptr, 0, flag, 0,
                                                nullptr, nullptr, 0, 0.f, 3 * NC);
    sw_logits_c<<<dim3(12, NC), 256, 0, stream>>>(qswb, CB1, swlog, c * NC);
  }
  sw_softmax<<<3072, 256, 0, stream>>>(swlog);

  pair_bias<<<36864, 256, 0, stream>>>(pair, c_lpg, c_lpb, c_wb, attnf, flag);
  for (int c = 0; c < nchunks; ++c) {
    size_t R = (size_t)c * NC * 384;
    // fused: q = LN(msa)@wq (mode 2, seq-weight in epilogue) -> CB1
    //        k = LN(msa)@wk * isd                             -> CB2
    gemmA<<<dim3(3 * NC * 4), 256, 0, stream>>>(mbf, R, wT + 2 * 65536, nullptr,
                                                CB1, 0, 2, 1.f, swlog, c * NC, flag, 0,
                                                wT + 3 * 65536, CB2, 0, isd, 3 * NC);
    qk_accum_c<<<dim3(72 * (NC / nlen)), 256, 0, stream>>>(CB1, CB2, attnf, nlen);
  }
  attn_softmax_k<<<3072, 384, 0, stream>>>(attnf, attnbf);

  for (int c = 0; c < nchunks; ++c) {
    size_t R = (size_t)c * NC * 384;
    // v = LN(msa) @ wv, written directly in vt (transposed) layout via mode 3
    gemmA<<<dim3(3 * NC * 2), 256, 0, stream>>>(mbf, R, wT + 4 * 65536, nullptr,
                                                CB2, 0, 3, 1.f, nullptr, 0, flag, 0,
                                                nullptr, nullptr, 0, 0.f, 3 * NC);
    pv_gemm<<<dim3(3, NC / 4, 8), 256, 0, stream>>>(attnbf, CB2, CB3);
    gemmA<<<dim3(3 * NC * 2), 256, 0, stream>>>(mbf, R, wT + 5 * 65536, c_bg,
                                                CB3, 0, 1, 1.f, nullptr, 0, flag, 0,
                                                nullptr, nullptr, 0, 0.f, 3 * NC);
    gemmA<<<dim3(3 * NC * 2), 256, 0, stream>>>(CB3, 0, wT + 6 * 65536, c_bo,
                                                d_out, R, 0, 1.f, nullptr, 0, flag, 1,
                                                nullptr, nullptr, 0, 0.f, 3 * NC);
  }
}